// Round 5
// baseline (500.918 us; speedup 1.0000x reference)
//
#include <hip/hip_runtime.h>

#define PTAB_STRIDE 64
typedef float f2 __attribute__((ext_vector_type(2)));

__device__ __forceinline__ f2 fma2(f2 a, f2 b, f2 c) {
    return __builtin_elementwise_fma(a, b, c);
}

// ---------------------------------------------------------------------------
// Phase 1: ptab[v][h] = dot(emb[v,:], W_ih[h,:]) + b_ih[h] + b_hh[h]
// Wave-private 8-row tiles. lane = (g = lane>>3 -> row, hq = lane&7 -> h-octet).
// One ds_read_b128 serves 8 rows (8 addrs x 8-lane bcast, conflict-free:
// stride 300 words -> banks {0,12,24,4,16,28,8,20}). W per-lane from global
// (L1/L2-hot), manually double-buffered in named regs. No barriers.
// ---------------------------------------------------------------------------
__global__ __launch_bounds__(256) void ptab_kernel(
    const float* __restrict__ emb, const float* __restrict__ Wih,
    const float* __restrict__ bih, const float* __restrict__ bhh,
    float* __restrict__ ptab)
{
    __shared__ float4 tile[4][600];                  // 38400 B
    const int tid  = threadIdx.x;
    const int lane = tid & 63;
    const int wid  = tid >> 6;
    const int g    = lane >> 3;                      // row group 0..7
    const int hq   = lane & 7;                       // h-octet 0..7

    const int wgid = blockIdx.x * 4 + wid;
    if (wgid >= 6250) return;                        // 50000/8 groups
    const int v0 = wgid * 8;

    // ---- stage this wave's 8 rows (2400 floats = 600 float4) into LDS ----
    const float4* src = (const float4*)(emb + (size_t)v0 * 300);
    float4* t = tile[wid];
    float4 s0 = src[lane],       s1 = src[lane + 64],  s2 = src[lane + 128];
    float4 s3 = src[lane + 192], s4 = src[lane + 256], s5 = src[lane + 320];
    float4 s6 = src[lane + 384], s7 = src[lane + 448], s8 = src[lane + 512];
    const bool e9 = lane < 24;                       // 600 - 9*64 = 24
    float4 s9;
    if (e9) s9 = src[lane + 576];
    t[lane]       = s0;  t[lane + 64]  = s1;  t[lane + 128] = s2;
    t[lane + 192] = s3;  t[lane + 256] = s4;  t[lane + 320] = s5;
    t[lane + 384] = s6;  t[lane + 448] = s7;  t[lane + 512] = s8;
    if (e9) t[lane + 576] = s9;
    // wave-private tile: compiler-inserted waitcnts suffice, no barrier

    // ---- W row pointers for this lane's 8 h's (clamped; h>=50 is garbage,
    //      written to unused ptab cols 50..63) ----
    const int hb = hq * 8;
    const float* wr0 = Wih + min(hb + 0, 49) * 300;
    const float* wr1 = Wih + min(hb + 1, 49) * 300;
    const float* wr2 = Wih + min(hb + 2, 49) * 300;
    const float* wr3 = Wih + min(hb + 3, 49) * 300;
    const float* wr4 = Wih + min(hb + 4, 49) * 300;
    const float* wr5 = Wih + min(hb + 5, 49) * 300;
    const float* wr6 = Wih + min(hb + 6, 49) * 300;
    const float* wr7 = Wih + min(hb + 7, 49) * 300;

    f2 acc0 = {0.f,0.f}, acc1 = {0.f,0.f}, acc2 = {0.f,0.f}, acc3 = {0.f,0.f};
    f2 acc4 = {0.f,0.f}, acc5 = {0.f,0.f}, acc6 = {0.f,0.f}, acc7 = {0.f,0.f};

    const float4* erow = &t[g * 75];

#define LOADW(P, kc)                                                    \
    P##0 = *(const float4*)(wr0 + (kc) * 4);                            \
    P##1 = *(const float4*)(wr1 + (kc) * 4);                            \
    P##2 = *(const float4*)(wr2 + (kc) * 4);                            \
    P##3 = *(const float4*)(wr3 + (kc) * 4);                            \
    P##4 = *(const float4*)(wr4 + (kc) * 4);                            \
    P##5 = *(const float4*)(wr5 + (kc) * 4);                            \
    P##6 = *(const float4*)(wr6 + (kc) * 4);                            \
    P##7 = *(const float4*)(wr7 + (kc) * 4);

#define FMA1(A, W, E)                                                   \
    A = fma2((f2){E.x, E.y}, (f2){W.x, W.y}, A);                        \
    A = fma2((f2){E.z, E.w}, (f2){W.z, W.w}, A);

#define FMAW(P, E)                                                      \
    FMA1(acc0, P##0, E)  FMA1(acc1, P##1, E)                            \
    FMA1(acc2, P##2, E)  FMA1(acc3, P##3, E)                            \
    FMA1(acc4, P##4, E)  FMA1(acc5, P##5, E)                            \
    FMA1(acc6, P##6, E)  FMA1(acc7, P##7, E)

    float4 wa0, wa1, wa2, wa3, wa4, wa5, wa6, wa7;
    float4 wb0, wb1, wb2, wb3, wb4, wb5, wb6, wb7;
    LOADW(wa, 0)

    #pragma unroll 1
    for (int it = 0; it < 37; ++it) {
        const int kcA = 2 * it, kcB = 2 * it + 1;
        LOADW(wb, kcB)
        {
            float4 e = erow[kcA];
            FMAW(wa, e)
        }
        LOADW(wa, kcB + 1)
        {
            float4 e = erow[kcB];
            FMAW(wb, e)
        }
    }
    {   // tail kc = 74 (uses wa loaded in last iteration)
        float4 e = erow[74];
        FMAW(wa, e)
    }
#undef LOADW
#undef FMA1
#undef FMAW

    // ---- epilogue: bias (clamped) + store 2 float4 per lane ----
    float o0 = acc0.x + acc0.y + bih[min(hb + 0, 49)] + bhh[min(hb + 0, 49)];
    float o1 = acc1.x + acc1.y + bih[min(hb + 1, 49)] + bhh[min(hb + 1, 49)];
    float o2 = acc2.x + acc2.y + bih[min(hb + 2, 49)] + bhh[min(hb + 2, 49)];
    float o3 = acc3.x + acc3.y + bih[min(hb + 3, 49)] + bhh[min(hb + 3, 49)];
    float o4 = acc4.x + acc4.y + bih[min(hb + 4, 49)] + bhh[min(hb + 4, 49)];
    float o5 = acc5.x + acc5.y + bih[min(hb + 5, 49)] + bhh[min(hb + 5, 49)];
    float o6 = acc6.x + acc6.y + bih[min(hb + 6, 49)] + bhh[min(hb + 6, 49)];
    float o7 = acc7.x + acc7.y + bih[min(hb + 7, 49)] + bhh[min(hb + 7, 49)];

    float* dst = ptab + (size_t)(v0 + g) * PTAB_STRIDE + hb;
    *(float4*)dst       = make_float4(o0, o1, o2, o3);
    *(float4*)(dst + 4) = make_float4(o4, o5, o6, o7);
}

// ---------------------------------------------------------------------------
// Phase 2: recurrence + head. One wave per batch element (unchanged, ~46us).
// h broadcast: 1 ds_write_b32 + 12 ds_read_b128 + 1 ds_read_b64 (uniform =
// LDS broadcast, same-wave in-order). Dot: 25 v_pk_fma_f32. Biases in ptab.
// ---------------------------------------------------------------------------
__global__ __launch_bounds__(64) void rnn_kernel(
    const int* __restrict__ tokens, const float* __restrict__ ptab,
    const float* __restrict__ Whh,
    const float* __restrict__ Wfc, const float* __restrict__ bfc,
    float* __restrict__ out)
{
    __shared__ int   stok[544];
    __shared__ float hbuf[64];
    const int lane = threadIdx.x;
    const int b    = blockIdx.x;
    const int hc   = lane < 50 ? lane : 49;

    #pragma unroll
    for (int k = 0; k < 8; ++k)
        stok[lane + 64 * k] = tokens[b * 512 + lane + 64 * k];
    if (lane < 32) stok[512 + lane] = 0;     // pad: token 0 -> valid row
    __syncthreads();

    f2 whh2[25];
    #pragma unroll
    for (int j = 0; j < 25; ++j) {
        float2 w2 = *(const float2*)(Whh + hc * 50 + 2 * j);
        whh2[j].x = w2.x; whh2[j].y = w2.y;
    }

    float h = 0.f;

#define GATHER(T) ptab[(size_t)(T) * PTAB_STRIDE + lane]

    float x0 = GATHER(stok[0]), x1 = GATHER(stok[1]);
    float x2 = GATHER(stok[2]), x3 = GATHER(stok[3]);
    float x4 = GATHER(stok[4]), x5 = GATHER(stok[5]);
    float x6 = GATHER(stok[6]), x7 = GATHER(stok[7]);
    int k0 = stok[8],  k1 = stok[9],  k2 = stok[10], k3 = stok[11];
    int k4 = stok[12], k5 = stok[13], k6 = stok[14], k7 = stok[15];

#define RNN_STEP(XV)                                                        \
    {                                                                       \
        hbuf[lane] = h;                    /* ds_write_b32, in-order */     \
        const float4* hb4 = (const float4*)hbuf;                            \
        float4 h0 = hb4[0], h1 = hb4[1], h2 = hb4[2];                       \
        float4 h3 = hb4[3], h4 = hb4[4], h5 = hb4[5];                       \
        float4 h6 = hb4[6], h7 = hb4[7], h8 = hb4[8];                       \
        float4 h9 = hb4[9], h10 = hb4[10], h11 = hb4[11];                   \
        float2 h12 = *(const float2*)&hbuf[48];                             \
        f2 a0 = {0.f, 0.f}, a1 = {0.f, 0.f};                                \
        a0 = fma2((f2){h0.x,  h0.y},  whh2[0],  a0);                        \
        a1 = fma2((f2){h0.z,  h0.w},  whh2[1],  a1);                        \
        a0 = fma2((f2){h1.x,  h1.y},  whh2[2],  a0);                        \
        a1 = fma2((f2){h1.z,  h1.w},  whh2[3],  a1);                        \
        a0 = fma2((f2){h2.x,  h2.y},  whh2[4],  a0);                        \
        a1 = fma2((f2){h2.z,  h2.w},  whh2[5],  a1);                        \
        a0 = fma2((f2){h3.x,  h3.y},  whh2[6],  a0);                        \
        a1 = fma2((f2){h3.z,  h3.w},  whh2[7],  a1);                        \
        a0 = fma2((f2){h4.x,  h4.y},  whh2[8],  a0);                        \
        a1 = fma2((f2){h4.z,  h4.w},  whh2[9],  a1);                        \
        a0 = fma2((f2){h5.x,  h5.y},  whh2[10], a0);                        \
        a1 = fma2((f2){h5.z,  h5.w},  whh2[11], a1);                        \
        a0 = fma2((f2){h6.x,  h6.y},  whh2[12], a0);                        \
        a1 = fma2((f2){h6.z,  h6.w},  whh2[13], a1);                        \
        a0 = fma2((f2){h7.x,  h7.y},  whh2[14], a0);                        \
        a1 = fma2((f2){h7.z,  h7.w},  whh2[15], a1);                        \
        a0 = fma2((f2){h8.x,  h8.y},  whh2[16], a0);                        \
        a1 = fma2((f2){h8.z,  h8.w},  whh2[17], a1);                        \
        a0 = fma2((f2){h9.x,  h9.y},  whh2[18], a0);                        \
        a1 = fma2((f2){h9.z,  h9.w},  whh2[19], a1);                        \
        a0 = fma2((f2){h10.x, h10.y}, whh2[20], a0);                        \
        a1 = fma2((f2){h10.z, h10.w}, whh2[21], a1);                        \
        a0 = fma2((f2){h11.x, h11.y}, whh2[22], a0);                        \
        a1 = fma2((f2){h11.z, h11.w}, whh2[23], a1);                        \
        a0 = fma2((f2){h12.x, h12.y}, whh2[24], a0);                        \
        f2 sv = a0 + a1;                                                    \
        float a = (XV) + (sv.x + sv.y);                                     \
        a = fminf(9.f, fmaxf(-9.f, a));                                     \
        float e = __expf(2.f * a);                                          \
        h = fmaf(-2.f, __builtin_amdgcn_rcpf(e + 1.f), 1.f);                \
    }

    for (int t = 0; t < 512; t += 8) {
        float n0 = GATHER(k0), n1 = GATHER(k1), n2 = GATHER(k2), n3 = GATHER(k3);
        float n4 = GATHER(k4), n5 = GATHER(k5), n6 = GATHER(k6), n7 = GATHER(k7);
        k0 = stok[t + 16]; k1 = stok[t + 17]; k2 = stok[t + 18]; k3 = stok[t + 19];
        k4 = stok[t + 20]; k5 = stok[t + 21]; k6 = stok[t + 22]; k7 = stok[t + 23];

        RNN_STEP(x0); RNN_STEP(x1); RNN_STEP(x2); RNN_STEP(x3);
        RNN_STEP(x4); RNN_STEP(x5); RNN_STEP(x6); RNN_STEP(x7);

        x0 = n0; x1 = n1; x2 = n2; x3 = n3;
        x4 = n4; x5 = n5; x6 = n6; x7 = n7;
    }
#undef RNN_STEP
#undef GATHER

    // ---- head: out[b][o] = sum_h h[h] * W_fc[o][h] + b_fc[o] ----
    float hv = (lane < 50) ? h : 0.f;
    #pragma unroll
    for (int o = 0; o < 4; ++o) {
        float w = (lane < 50) ? Wfc[o * 50 + lane] : 0.f;
        float p = hv * w;
        #pragma unroll
        for (int s = 32; s > 0; s >>= 1) p += __shfl_xor(p, s, 64);
        if (lane == 0) out[b * 4 + o] = p + bfc[o];
    }
}

extern "C" void kernel_launch(void* const* d_in, const int* in_sizes, int n_in,
                              void* d_out, int out_size, void* d_ws, size_t ws_size,
                              hipStream_t stream)
{
    const int*   tokens = (const int*)d_in[0];
    const float* emb    = (const float*)d_in[1];
    const float* Wih    = (const float*)d_in[2];
    const float* Whh    = (const float*)d_in[3];
    const float* bih    = (const float*)d_in[4];
    const float* bhh    = (const float*)d_in[5];
    const float* Wfc    = (const float*)d_in[6];
    const float* bfc    = (const float*)d_in[7];

    float* ptab = (float*)d_ws;          // 50000 * 64 * 4 B = 12.8 MB
    float* outp = (float*)d_out;

    ptab_kernel<<<1563, 256, 0, stream>>>(emb, Wih, bih, bhh, ptab);
    rnn_kernel<<<256, 64, 0, stream>>>(tokens, ptab, Whh, Wfc, bfc, outp);
}

// Round 6
// 353.208 us; speedup vs baseline: 1.4182x; 1.4182x over previous
//
#include <hip/hip_runtime.h>

#define PTAB_STRIDE 64
typedef float f2 __attribute__((ext_vector_type(2)));

__device__ __forceinline__ f2 fma2(f2 a, f2 b, f2 c) {
    return __builtin_elementwise_fma(a, b, c);
}

// ---------------------------------------------------------------------------
// Phase 1: ptab[v][h] = dot(emb[v,:], W_ih[h,:]) + b_ih[h] + b_hh[h]
// 2-wave blocks; each wave privately owns 16 vocab rows staged in LDS.
// lane = (g = lane>>3, hq = lane&7): lane computes rows {g, g+8} x h-octet hq.
// emb via ds_read_b128 shared by 8 rows (conflict-free: stride 1200 B ->
// banks {0,12,24,4,16,28,8,20}). W streamed per-lane from global (L2-hot)
// through a 3-deep register ring (96 VGPR) -> load-use distance ~150 cyc.
// __launch_bounds__(128,2) so the ring survives regalloc (round-5 lesson:
// default heuristic gave 68 VGPR and serialized every W load).
// ---------------------------------------------------------------------------
__global__ __launch_bounds__(128, 2) void ptab_kernel(
    const float* __restrict__ emb, const float* __restrict__ Wih,
    const float* __restrict__ bih, const float* __restrict__ bhh,
    float* __restrict__ ptab)
{
    __shared__ __align__(16) float4 tile[2][1200];   // 2 x 19200 B
    const int tid  = threadIdx.x;
    const int lane = tid & 63;
    const int wid  = tid >> 6;
    const int g    = lane >> 3;                      // row in group 0..7
    const int hq   = lane & 7;                       // h-octet 0..7

    const int wgid = blockIdx.x * 2 + wid;
    if (wgid >= 3125) return;                        // 50000 / 16 rows exact
    const int v0 = wgid * 16;

    // ---- stage this wave's 16 rows (4800 floats = 1200 float4) into LDS ----
    const float4* src = (const float4*)(emb + (size_t)v0 * 300);
    float4* t = tile[wid];
    #pragma unroll
    for (int j = 0; j < 18; ++j) t[lane + 64 * j] = src[lane + 64 * j];
    if (lane < 48) t[lane + 1152] = src[lane + 1152];
    // wave-private tile: compiler-inserted waitcnts order write->read.

    // ---- W row pointers for this lane's 8 h's (clamped; h>=50 -> cols 50..63
    //      of ptab, never read by rnn) ----
    const int hb = hq * 8;
    const float* wr[8];
    #pragma unroll
    for (int r = 0; r < 8; ++r) wr[r] = Wih + min(hb + r, 49) * 300;

    f2 accA[8], accB[8];
    #pragma unroll
    for (int r = 0; r < 8; ++r) { accA[r] = (f2){0.f, 0.f}; accB[r] = (f2){0.f, 0.f}; }

    const float4* erow1 = t + g * 75;
    const float4* erow2 = t + (g + 8) * 75;

#define LOADW(P, kc)                                                        \
    { _Pragma("unroll")                                                     \
      for (int r = 0; r < 8; ++r) P[r] = *(const float4*)(wr[r] + (kc) * 4); }

#define FMACHUNK(P, kc)                                                     \
    { float4 e1 = erow1[kc];                                                \
      float4 e2 = erow2[kc];                                                \
      _Pragma("unroll")                                                     \
      for (int r = 0; r < 8; ++r) {                                         \
          accA[r] = fma2((f2){e1.x, e1.y}, (f2){P[r].x, P[r].y}, accA[r]);  \
          accA[r] = fma2((f2){e1.z, e1.w}, (f2){P[r].z, P[r].w}, accA[r]);  \
          accB[r] = fma2((f2){e2.x, e2.y}, (f2){P[r].x, P[r].y}, accB[r]);  \
          accB[r] = fma2((f2){e2.z, e2.w}, (f2){P[r].z, P[r].w}, accB[r]);  \
      } }

    float4 wA[8], wB[8], wC[8];
    LOADW(wA, 0) LOADW(wB, 1) LOADW(wC, 2)

    #pragma unroll 1
    for (int it = 0; it < 24; ++it) {
        const int k0 = 3 * it;
        FMACHUNK(wA, k0)      LOADW(wA, k0 + 3)
        FMACHUNK(wB, k0 + 1)  LOADW(wB, k0 + 4)
        FMACHUNK(wC, k0 + 2)  LOADW(wC, k0 + 5)
    }
    FMACHUNK(wA, 72) FMACHUNK(wB, 73) FMACHUNK(wC, 74)
#undef LOADW
#undef FMACHUNK

    // ---- epilogue: bias (clamped) + 2 float4 stores per row ----
    float ob[8];
    #pragma unroll
    for (int r = 0; r < 8; ++r) {
        const int h = min(hb + r, 49);
        ob[r] = bih[h] + bhh[h];
    }
    float oA[8], oB[8];
    #pragma unroll
    for (int r = 0; r < 8; ++r) {
        oA[r] = accA[r].x + accA[r].y + ob[r];
        oB[r] = accB[r].x + accB[r].y + ob[r];
    }
    float* dstA = ptab + (size_t)(v0 + g)     * PTAB_STRIDE + hb;
    float* dstB = ptab + (size_t)(v0 + g + 8) * PTAB_STRIDE + hb;
    *(float4*)dstA       = make_float4(oA[0], oA[1], oA[2], oA[3]);
    *(float4*)(dstA + 4) = make_float4(oA[4], oA[5], oA[6], oA[7]);
    *(float4*)dstB       = make_float4(oB[0], oB[1], oB[2], oB[3]);
    *(float4*)(dstB + 4) = make_float4(oB[4], oB[5], oB[6], oB[7]);
}

// ---------------------------------------------------------------------------
// Phase 2: recurrence + head. One wave per batch element (measured ~46us).
// h broadcast: 1 ds_write_b32 + 12 ds_read_b128 + 1 ds_read_b64 (uniform =
// LDS broadcast, same-wave in-order). Dot: 25 v_pk_fma_f32. Biases in ptab.
// ---------------------------------------------------------------------------
__global__ __launch_bounds__(64) void rnn_kernel(
    const int* __restrict__ tokens, const float* __restrict__ ptab,
    const float* __restrict__ Whh,
    const float* __restrict__ Wfc, const float* __restrict__ bfc,
    float* __restrict__ out)
{
    __shared__ int   stok[544];
    __shared__ float hbuf[64];
    const int lane = threadIdx.x;
    const int b    = blockIdx.x;
    const int hc   = lane < 50 ? lane : 49;

    #pragma unroll
    for (int k = 0; k < 8; ++k)
        stok[lane + 64 * k] = tokens[b * 512 + lane + 64 * k];
    if (lane < 32) stok[512 + lane] = 0;     // pad: token 0 -> valid row
    __syncthreads();

    f2 whh2[25];
    #pragma unroll
    for (int j = 0; j < 25; ++j) {
        float2 w2 = *(const float2*)(Whh + hc * 50 + 2 * j);
        whh2[j].x = w2.x; whh2[j].y = w2.y;
    }

    float h = 0.f;

#define GATHER(T) ptab[(size_t)(T) * PTAB_STRIDE + lane]

    float x0 = GATHER(stok[0]), x1 = GATHER(stok[1]);
    float x2 = GATHER(stok[2]), x3 = GATHER(stok[3]);
    float x4 = GATHER(stok[4]), x5 = GATHER(stok[5]);
    float x6 = GATHER(stok[6]), x7 = GATHER(stok[7]);
    int k0 = stok[8],  k1 = stok[9],  k2 = stok[10], k3 = stok[11];
    int k4 = stok[12], k5 = stok[13], k6 = stok[14], k7 = stok[15];

#define RNN_STEP(XV)                                                        \
    {                                                                       \
        hbuf[lane] = h;                    /* ds_write_b32, in-order */     \
        const float4* hb4 = (const float4*)hbuf;                            \
        float4 h0 = hb4[0], h1 = hb4[1], h2 = hb4[2];                       \
        float4 h3 = hb4[3], h4 = hb4[4], h5 = hb4[5];                       \
        float4 h6 = hb4[6], h7 = hb4[7], h8 = hb4[8];                       \
        float4 h9 = hb4[9], h10 = hb4[10], h11 = hb4[11];                   \
        float2 h12 = *(const float2*)&hbuf[48];                             \
        f2 a0 = {0.f, 0.f}, a1 = {0.f, 0.f};                                \
        a0 = fma2((f2){h0.x,  h0.y},  whh2[0],  a0);                        \
        a1 = fma2((f2){h0.z,  h0.w},  whh2[1],  a1);                        \
        a0 = fma2((f2){h1.x,  h1.y},  whh2[2],  a0);                        \
        a1 = fma2((f2){h1.z,  h1.w},  whh2[3],  a1);                        \
        a0 = fma2((f2){h2.x,  h2.y},  whh2[4],  a0);                        \
        a1 = fma2((f2){h2.z,  h2.w},  whh2[5],  a1);                        \
        a0 = fma2((f2){h3.x,  h3.y},  whh2[6],  a0);                        \
        a1 = fma2((f2){h3.z,  h3.w},  whh2[7],  a1);                        \
        a0 = fma2((f2){h4.x,  h4.y},  whh2[8],  a0);                        \
        a1 = fma2((f2){h4.z,  h4.w},  whh2[9],  a1);                        \
        a0 = fma2((f2){h5.x,  h5.y},  whh2[10], a0);                        \
        a1 = fma2((f2){h5.z,  h5.w},  whh2[11], a1);                        \
        a0 = fma2((f2){h6.x,  h6.y},  whh2[12], a0);                        \
        a1 = fma2((f2){h6.z,  h6.w},  whh2[13], a1);                        \
        a0 = fma2((f2){h7.x,  h7.y},  whh2[14], a0);                        \
        a1 = fma2((f2){h7.z,  h7.w},  whh2[15], a1);                        \
        a0 = fma2((f2){h8.x,  h8.y},  whh2[16], a0);                        \
        a1 = fma2((f2){h8.z,  h8.w},  whh2[17], a1);                        \
        a0 = fma2((f2){h9.x,  h9.y},  whh2[18], a0);                        \
        a1 = fma2((f2){h9.z,  h9.w},  whh2[19], a1);                        \
        a0 = fma2((f2){h10.x, h10.y}, whh2[20], a0);                        \
        a1 = fma2((f2){h10.z, h10.w}, whh2[21], a1);                        \
        a0 = fma2((f2){h11.x, h11.y}, whh2[22], a0);                        \
        a1 = fma2((f2){h11.z, h11.w}, whh2[23], a1);                        \
        a0 = fma2((f2){h12.x, h12.y}, whh2[24], a0);                        \
        f2 sv = a0 + a1;                                                    \
        float a = (XV) + (sv.x + sv.y);                                     \
        a = fminf(9.f, fmaxf(-9.f, a));                                     \
        float e = __expf(2.f * a);                                          \
        h = fmaf(-2.f, __builtin_amdgcn_rcpf(e + 1.f), 1.f);                \
    }

    for (int t = 0; t < 512; t += 8) {
        float n0 = GATHER(k0), n1 = GATHER(k1), n2 = GATHER(k2), n3 = GATHER(k3);
        float n4 = GATHER(k4), n5 = GATHER(k5), n6 = GATHER(k6), n7 = GATHER(k7);
        k0 = stok[t + 16]; k1 = stok[t + 17]; k2 = stok[t + 18]; k3 = stok[t + 19];
        k4 = stok[t + 20]; k5 = stok[t + 21]; k6 = stok[t + 22]; k7 = stok[t + 23];

        RNN_STEP(x0); RNN_STEP(x1); RNN_STEP(x2); RNN_STEP(x3);
        RNN_STEP(x4); RNN_STEP(x5); RNN_STEP(x6); RNN_STEP(x7);

        x0 = n0; x1 = n1; x2 = n2; x3 = n3;
        x4 = n4; x5 = n5; x6 = n6; x7 = n7;
    }
#undef RNN_STEP
#undef GATHER

    // ---- head: out[b][o] = sum_h h[h] * W_fc[o][h] + b_fc[o] ----
    float hv = (lane < 50) ? h : 0.f;
    #pragma unroll
    for (int o = 0; o < 4; ++o) {
        float w = (lane < 50) ? Wfc[o * 50 + lane] : 0.f;
        float p = hv * w;
        #pragma unroll
        for (int s = 32; s > 0; s >>= 1) p += __shfl_xor(p, s, 64);
        if (lane == 0) out[b * 4 + o] = p + bfc[o];
    }
}

extern "C" void kernel_launch(void* const* d_in, const int* in_sizes, int n_in,
                              void* d_out, int out_size, void* d_ws, size_t ws_size,
                              hipStream_t stream)
{
    const int*   tokens = (const int*)d_in[0];
    const float* emb    = (const float*)d_in[1];
    const float* Wih    = (const float*)d_in[2];
    const float* Whh    = (const float*)d_in[3];
    const float* bih    = (const float*)d_in[4];
    const float* bhh    = (const float*)d_in[5];
    const float* Wfc    = (const float*)d_in[6];
    const float* bfc    = (const float*)d_in[7];

    float* ptab = (float*)d_ws;          // 50000 * 64 * 4 B = 12.8 MB
    float* outp = (float*)d_out;

    ptab_kernel<<<1563, 128, 0, stream>>>(emb, Wih, bih, bhh, ptab);
    rnn_kernel<<<256, 64, 0, stream>>>(tokens, ptab, Whh, Wfc, bfc, outp);
}